// Round 5
// baseline (1016.280 us; speedup 1.0000x reference)
//
#include <hip/hip_runtime.h>
#include <hip/hip_bf16.h>
#include <hip/hip_fp16.h>

#ifndef MINi
#define MINi(a,b) ((a)<(b)?(a):(b))
#endif

typedef _Float16 f16x8 __attribute__((ext_vector_type(8)));
typedef _Float16 f16x4 __attribute__((ext_vector_type(4)));
typedef float    f32x4 __attribute__((ext_vector_type(4)));

// ---------------------------------------------------------------------------
// Kernel 1: prep = cvt(xin->fp16) + Wt transpose x3 + zero(cnt,status)
// block ranges: [0,ncvt) cvt | [ncvt,ncvt+192) wt | rest: zero
// ---------------------------------------------------------------------------
__global__ __launch_bounds__(256)
void prep_kernel(const float* __restrict__ xin, _Float16* __restrict__ Xh,
                 const float* __restrict__ W1, const float* __restrict__ W2,
                 const float* __restrict__ W3,
                 _Float16* __restrict__ Wt1, _Float16* __restrict__ Wt2,
                 _Float16* __restrict__ Wt3,
                 int* __restrict__ zbase, int n4, int ncvt, int nzero)
{
    int b = blockIdx.x;
    int t = threadIdx.x;
    if (b < ncvt) {
        int i = b * 256 + t;
        if (i < n4) {
            float4 v = ((const float4*)xin)[i];
            f16x4 st = {(_Float16)v.x, (_Float16)v.y, (_Float16)v.z, (_Float16)v.w};
            ((f16x4*)Xh)[i] = st;
        }
    } else if (b < ncvt + 192) {
        int wb = b - ncvt;
        int wi = wb >> 6;                       // 0,1,2
        int idx = (wb & 63) * 256 + t;          // 0..16383
        const float* W = (wi == 0) ? W1 : (wi == 1) ? W2 : W3;
        _Float16* Wt = (wi == 0) ? Wt1 : (wi == 1) ? Wt2 : Wt3;
        int k = idx >> 7, col = idx & 127;
        Wt[col * 128 + k] = (_Float16)W[idx];
    } else {
        int i = (b - ncvt - 192) * 256 + t;
        if (i < nzero) zbase[i] = 0;            // cnt (N) + scan status (nb), contiguous
    }
}

// ---------------------------------------------------------------------------
// Kernel 2: degree count
// ---------------------------------------------------------------------------
__global__ __launch_bounds__(256)
void deg_kernel(const int* __restrict__ ei, int* __restrict__ cnt, int nE)
{
    int e = blockIdx.x * 256 + threadIdx.x;
    if (e >= nE) return;
    int2 p = ((const int2*)ei)[e];   // (src, dst)
    atomicAdd(&cnt[p.y], 1);
}

// ---------------------------------------------------------------------------
// Kernel 3: single-pass scan with decoupled lookback.
// status[b]: 0 = empty, (1<<30)|aggregate, (2<<30)|inclusive  (sums < 2^21)
// ---------------------------------------------------------------------------
#define FLAG_AGG (1u << 30)
#define FLAG_INC (2u << 30)
#define VAL_MASK 0x3FFFFFFFu

__global__ __launch_bounds__(256)
void scan_kernel(const int* __restrict__ cnt, int* __restrict__ row_start,
                 int* __restrict__ cursor, float* __restrict__ dinv,
                 unsigned* __restrict__ status, int n, int nE)
{
    __shared__ int tsum[256];
    __shared__ int sbase;
    int b = blockIdx.x;
    int t = threadIdx.x;
    int base = b * 1024;

    int c[4]; int s = 0;
    #pragma unroll
    for (int i = 0; i < 4; ++i) {
        int idx = base + t * 4 + i;
        c[i] = (idx < n) ? cnt[idx] : 0;
        s += c[i];
    }
    tsum[t] = s;
    __syncthreads();
    for (int off = 1; off < 256; off <<= 1) {
        int add = (t >= off) ? tsum[t - off] : 0;
        __syncthreads();
        tsum[t] += add;
        __syncthreads();
    }

    if (t == 0) {
        int total = tsum[255];
        if (b == 0) {
            __hip_atomic_store(&status[0], FLAG_INC | (unsigned)total,
                               __ATOMIC_RELAXED, __HIP_MEMORY_SCOPE_AGENT);
            sbase = 0;
        } else {
            __hip_atomic_store(&status[b], FLAG_AGG | (unsigned)total,
                               __ATOMIC_RELAXED, __HIP_MEMORY_SCOPE_AGENT);
            int run = 0;
            int j = b - 1;
            while (true) {
                unsigned w = __hip_atomic_load(&status[j], __ATOMIC_RELAXED,
                                               __HIP_MEMORY_SCOPE_AGENT);
                if (w == 0u) { __builtin_amdgcn_s_sleep(1); continue; }
                run += (int)(w & VAL_MASK);
                if (w & FLAG_INC) break;
                --j;
            }
            int inc = run + total;
            __hip_atomic_store(&status[b], FLAG_INC | (unsigned)inc,
                               __ATOMIC_RELAXED, __HIP_MEMORY_SCOPE_AGENT);
            sbase = inc - total;
        }
    }
    __syncthreads();

    int run = sbase + tsum[t] - s;   // exclusive prefix for this thread
    #pragma unroll
    for (int i = 0; i < 4; ++i) {
        int idx = base + t * 4 + i;
        if (idx < n) {
            row_start[idx] = run;
            cursor[idx]    = run;
            dinv[idx]      = rsqrtf((float)(c[i] + 1));   // +1 self-loop
            run += c[i];
        }
    }
    if (b == 0 && t == 0) row_start[n] = nE;
}

// ---------------------------------------------------------------------------
// Kernel 4: CSR fill
// ---------------------------------------------------------------------------
__global__ __launch_bounds__(256)
void fill_kernel(const int* __restrict__ ei, const float* __restrict__ dinv,
                 int* __restrict__ cursor, int2* __restrict__ csr, int nE)
{
    int e = blockIdx.x * 256 + threadIdx.x;
    if (e >= nE) return;
    int2 p = ((const int2*)ei)[e];
    int pos = atomicAdd(&cursor[p.y], 1);
    float nw = dinv[p.x] * dinv[p.y];
    csr[pos] = make_int2(p.x, __float_as_int(nw));
}

// ---------------------------------------------------------------------------
// Kernel 5: FUSED layer = aggregation (into LDS) + MFMA GEMM + bias + relu.
// Block = 256 thr = 4 waves = 32 nodes x 2 batches = 64 rows.
// Agg: wave wv handles nodes d0+wv*8..+7; lane 0-31 batch0 / 32-63 batch1,
//      each lane owns 4 feats. Result -> LDS al[64][136] (pitch 136 fp16,
//      16B-aligned rows; node-local row = hb*32 + node).
// GEMM: wave wv computes LDS rows [wv*16,wv*16+16) x all 128 cols with
//      mfma_f32_16x16x32_f16; A frag from LDS, B frags from Wt[col][k] (L1-hot).
//      C layout (m89): col = l&15, row = (l>>4)*4 + reg.
// ---------------------------------------------------------------------------
template<bool HALF_OUT>
__global__ __launch_bounds__(256)
void fused_kernel(const _Float16* __restrict__ x, void* __restrict__ outp,
                  const _Float16* __restrict__ Wt, const float* __restrict__ bias,
                  const int* __restrict__ row_start, const int2* __restrict__ csr,
                  const float* __restrict__ dinv, int n)
{
    __shared__ _Float16 al[64][136];
    int t    = threadIdx.x;
    int wv   = t >> 6;
    int lane = t & 63;
    int hb   = lane >> 5;                 // batch index
    int fo   = (lane & 31) << 2;          // feature offset (4 feats)
    int d0   = blockIdx.x << 5;           // 32 nodes per block
    const _Float16* xb = x + (size_t)hb * n * 128 + fo;

    // ---- aggregation phase ----
    for (int ni = 0; ni < 8; ++ni) {
        int d = d0 + wv * 8 + ni;
        float sd = dinv[d], s2 = sd * sd;
        f16x4 xs = *(const f16x4*)(xb + (size_t)d * 128);
        float a0 = s2 * (float)xs[0], a1 = s2 * (float)xs[1];
        float a2 = s2 * (float)xs[2], a3 = s2 * (float)xs[3];

        int rs = row_start[d], re = row_start[d + 1];
        for (int e = rs; e < re; e += 64) {
            int idx = e + lane;
            int2 pk = csr[idx < re ? idx : re - 1];
            int cntv = MINi(re - e, 64);
            #pragma unroll 4
            for (int i = 0; i < cntv; ++i) {
                int   src = __shfl(pk.x, i);
                float nw  = __shfl(__int_as_float(pk.y), i);
                f16x4 rv = *(const f16x4*)(xb + (size_t)src * 128);
                a0 += nw * (float)rv[0]; a1 += nw * (float)rv[1];
                a2 += nw * (float)rv[2]; a3 += nw * (float)rv[3];
            }
        }
        int lrow = hb * 32 + wv * 8 + ni;
        f16x4 st = {(_Float16)a0, (_Float16)a1, (_Float16)a2, (_Float16)a3};
        *(f16x4*)&al[lrow][fo] = st;
    }
    __syncthreads();

    // ---- GEMM phase ----
    int lr = lane & 15;
    int lk = lane >> 4;

    f16x8 af[4];
    #pragma unroll
    for (int ks = 0; ks < 4; ++ks)
        af[ks] = *(const f16x8*)&al[wv * 16 + lr][ks * 32 + lk * 8];

    f32x4 acc[8];
    #pragma unroll
    for (int nt = 0; nt < 8; ++nt) acc[nt] = (f32x4){0.f, 0.f, 0.f, 0.f};

    #pragma unroll
    for (int ks = 0; ks < 4; ++ks) {
        #pragma unroll
        for (int nt = 0; nt < 8; ++nt) {
            f16x8 bf = *(const f16x8*)(Wt + (size_t)(nt * 16 + lr) * 128 + ks * 32 + lk * 8);
            acc[nt] = __builtin_amdgcn_mfma_f32_16x16x32_f16(af[ks], bf, acc[nt], 0, 0, 0);
        }
    }

    #pragma unroll
    for (int nt = 0; nt < 8; ++nt) {
        float bc = bias[nt * 16 + lr];
        #pragma unroll
        for (int r = 0; r < 4; ++r) {
            float v = fmaxf(acc[nt][r] + bc, 0.f);
            int lrow = wv * 16 + lk * 4 + r;
            size_t grow = (size_t)(lrow >> 5) * n + d0 + (lrow & 31);
            if constexpr (HALF_OUT)
                ((_Float16*)outp)[grow * 128 + nt * 16 + lr] = (_Float16)v;
            else
                ((float*)outp)[grow * 128 + nt * 16 + lr] = v;
        }
    }
}

// ---------------------------------------------------------------------------
static inline size_t align_up(size_t x, size_t a) { return (x + a - 1) & ~(a - 1); }

extern "C" void kernel_launch(void* const* d_in, const int* in_sizes, int n_in,
                              void* d_out, int out_size, void* d_ws, size_t ws_size,
                              hipStream_t stream)
{
    const float* xin = (const float*)d_in[0];
    const int*   ei  = (const int*)d_in[1];
    const float* W1  = (const float*)d_in[2];
    const float* b1  = (const float*)d_in[3];
    const float* W2  = (const float*)d_in[4];
    const float* b2  = (const float*)d_in[5];
    const float* W3  = (const float*)d_in[6];
    const float* b3  = (const float*)d_in[7];
    float* out = (float*)d_out;

    const int N = in_sizes[0] / 256;   // 100000
    const int E = in_sizes[1] / 2;     // 1600000
    const int ROWS = 2 * N;
    const int nb = (N + 1023) / 1024;  // 98 scan blocks

    char* ws = (char*)d_ws;
    size_t off = 0;
    _Float16* Xh = (_Float16*)(ws + off);   off = align_up(off + (size_t)ROWS * 128 * 2, 256);
    _Float16* Xn = (_Float16*)(ws + off);   off = align_up(off + (size_t)ROWS * 128 * 2, 256);
    _Float16* Wt1 = (_Float16*)(ws + off);  off = align_up(off + 16384 * 2, 256);
    _Float16* Wt2 = (_Float16*)(ws + off);  off = align_up(off + 16384 * 2, 256);
    _Float16* Wt3 = (_Float16*)(ws + off);  off = align_up(off + 16384 * 2, 256);
    int* cnt = (int*)(ws + off);            off += (size_t)N * 4;                    // contiguous
    unsigned* status = (unsigned*)(ws + off); off = align_up(off + (size_t)nb * 4, 256); // with cnt
    int* row_start = (int*)(ws + off);      off = align_up(off + (size_t)(N + 1) * 4, 256);
    int* cursor = (int*)(ws + off);         off = align_up(off + (size_t)N * 4, 256);
    float* dinvp = (float*)(ws + off);      off = align_up(off + (size_t)N * 4, 256);
    int2* csr = (int2*)(ws + off);          off = align_up(off + (size_t)E * 8, 256);

    // ---- prep: cvt + Wt x3 + zero(cnt,status) ----
    const int n4 = ROWS * 32;                       // 6.4M float4
    const int ncvt = (n4 + 255) / 256;              // 25000
    const int nzero = N + nb;
    const int nzb = (nzero + 255) / 256;
    prep_kernel<<<ncvt + 192 + nzb, 256, 0, stream>>>(
        xin, Xh, W1, W2, W3, Wt1, Wt2, Wt3, cnt, n4, ncvt, nzero);

    // ---- build CSR ----
    deg_kernel<<<(E + 255) / 256, 256, 0, stream>>>(ei, cnt, E);
    scan_kernel<<<nb, 256, 0, stream>>>(cnt, row_start, cursor, dinvp, status, N, E);
    fill_kernel<<<(E + 255) / 256, 256, 0, stream>>>(ei, dinvp, cursor, csr, E);

    // ---- 3 fused layers ----
    const int fgrid = N / 32;   // 3125, exact
    fused_kernel<true><<<fgrid, 256, 0, stream>>>(Xh, Xn, Wt1, b1, row_start, csr, dinvp, N);
    fused_kernel<true><<<fgrid, 256, 0, stream>>>(Xn, Xh, Wt2, b2, row_start, csr, dinvp, N);
    fused_kernel<false><<<fgrid, 256, 0, stream>>>(Xh, out, Wt3, b3, row_start, csr, dinvp, N);
}